// Round 2
// baseline (370.238 us; speedup 1.0000x reference)
//
#include <hip/hip_runtime.h>
#include <hip/hip_bf16.h>

typedef __bf16 bf16;
typedef _Float16 half_t;
typedef bf16 bf16x8 __attribute__((ext_vector_type(8)));
typedef bf16 bf16x4 __attribute__((ext_vector_type(4)));
typedef float floatx4 __attribute__((ext_vector_type(4)));

#define B_ 32
#define N_ 196
#define H_ 8
#define D_ 1024
#define DK_ 128
#define BN_ (B_ * N_)   // 6272
#define BH_ (B_ * H_)   // 256
#define NPAD_ 224       // padded N for S rows / Vt cols
#define PSTRIDE_ 232    // LDS P-tile col stride (16B aligned, bank-spread)

#define MT_ 49          // M tiles (BM=128), 6272 = 49*128 exact
#define NTILE_ 4        // N tiles (BN=256), 1024 = 4*256 exact
#define KT_ 16          // K tiles (BK=64), 1024 = 16*64 exact

typedef __attribute__((address_space(3))) unsigned int lds_uint;
typedef const __attribute__((address_space(1))) unsigned int glb_uint;

__device__ __forceinline__ void async_copy16(const bf16* g, bf16* l) {
  __builtin_amdgcn_global_load_lds((glb_uint*)g, (lds_uint*)l, 16, 0, 0);
}

__device__ __forceinline__ bf16x8 bzero8() {
  bf16x8 z;
#pragma unroll
  for (int i = 0; i < 8; i++) z[i] = (bf16)0.0f;
  return z;
}

#define BARRIER() asm volatile("s_barrier" ::: "memory")
#define WAITV6() asm volatile("s_waitcnt vmcnt(6)" ::: "memory")
#define WAITV0() asm volatile("s_waitcnt vmcnt(0)" ::: "memory")

// ---------------------------------------------------------------------------
// Batched f32 -> bf16 convert: blockIdx.y selects which tensor (same size).
// ---------------------------------------------------------------------------
__global__ __launch_bounds__(256) void cvt3_kernel(const float* __restrict__ s0,
                                                   const float* __restrict__ s1,
                                                   const float* __restrict__ s2,
                                                   bf16* __restrict__ d0,
                                                   bf16* __restrict__ d1,
                                                   bf16* __restrict__ d2, int n4) {
  const int which = blockIdx.y;
  const float* s = (which == 0) ? s0 : (which == 1) ? s1 : s2;
  bf16* d = (which == 0) ? d0 : (which == 1) ? d1 : d2;
  int i = blockIdx.x * 256 + threadIdx.x;
  if (i >= n4) return;
  float4 v = ((const float4*)s)[i];
  bf16x4 o;
  o[0] = (bf16)v.x;
  o[1] = (bf16)v.y;
  o[2] = (bf16)v.z;
  o[3] = (bf16)v.w;
  *(bf16x4*)(d + (size_t)i * 4) = o;
}

__global__ __launch_bounds__(256) void cvt4_kernel(const float* __restrict__ s0,
                                                   const float* __restrict__ s1,
                                                   const float* __restrict__ s2,
                                                   const float* __restrict__ s3,
                                                   bf16* __restrict__ d0,
                                                   bf16* __restrict__ d1,
                                                   bf16* __restrict__ d2,
                                                   bf16* __restrict__ d3, int n4) {
  const int which = blockIdx.y;
  const float* s = (which == 0) ? s0 : (which == 1) ? s1 : (which == 2) ? s2 : s3;
  bf16* d = (which == 0) ? d0 : (which == 1) ? d1 : (which == 2) ? d2 : d3;
  int i = blockIdx.x * 256 + threadIdx.x;
  if (i >= n4) return;
  float4 v = ((const float4*)s)[i];
  bf16x4 o;
  o[0] = (bf16)v.x;
  o[1] = (bf16)v.y;
  o[2] = (bf16)v.z;
  o[3] = (bf16)v.w;
  *(bf16x4*)(d + (size_t)i * 4) = o;
}

// ---------------------------------------------------------------------------
// Geometry weights (LINEAR domain): S[b,h,n,m] = max(relu(geo . WG_w[h] + b), 1e-6)
// stored f16. softmax(log w + s) == w*exp(s)/sum(w*exp(s)), so attn multiplies.
// ---------------------------------------------------------------------------
__global__ __launch_bounds__(256) void geo_kernel(const float* __restrict__ box,
                                                  const float* __restrict__ WGw,
                                                  const float* __restrict__ WGb,
                                                  half_t* __restrict__ S) {
  __shared__ float4 wsh[128];
  if (threadIdx.x < 128) wsh[threadIdx.x] = ((const float4*)WGw)[threadIdx.x];
  __syncthreads();

  int tid = blockIdx.x * 256 + threadIdx.x;
  int b = tid / (N_ * N_);
  int rem = tid - b * (N_ * N_);
  int n = rem / N_;
  int m = rem - n * N_;

  float4 bn = ((const float4*)box)[b * N_ + n];
  float4 bm = ((const float4*)box)[b * N_ + m];
  float cxn = (bn.x + bn.z) * 0.5f, cyn = (bn.y + bn.w) * 0.5f;
  float wn = bn.z - bn.x + 1.0f, hn = bn.w - bn.y + 1.0f;
  float cxm = (bm.x + bm.z) * 0.5f, cym = (bm.y + bm.w) * 0.5f;
  float wm = bm.z - bm.x + 1.0f, hm = bm.w - bm.y + 1.0f;

  float pos[4];
  pos[0] = __logf(fmaxf(fabsf((cxn - cxm) / wn), 1e-3f));
  pos[1] = __logf(fmaxf(fabsf((cyn - cym) / hn), 1e-3f));
  pos[2] = __logf(wn / wm);
  pos[3] = __logf(hn / hm);

  const float dims[8] = {1.0f,          0.4216965034f, 0.1778279410f, 0.0749894209f,
                         0.0316227766f, 0.0133352143f, 0.0056234133f, 0.0023713737f};
  float feat[64];
#pragma unroll
  for (int p = 0; p < 4; p++) {
#pragma unroll
    for (int f = 0; f < 8; f++) {
      float a = 100.0f * pos[p] * dims[f];
      feat[p * 8 + f] = __sinf(a);
      feat[32 + p * 8 + f] = __cosf(a);
    }
  }
#pragma unroll
  for (int hh = 0; hh < 8; hh++) {
    float accv = WGb[hh];
#pragma unroll
    for (int g4 = 0; g4 < 16; g4++) {
      float4 wv = wsh[hh * 16 + g4];
      accv += feat[g4 * 4 + 0] * wv.x + feat[g4 * 4 + 1] * wv.y +
              feat[g4 * 4 + 2] * wv.z + feat[g4 * 4 + 3] * wv.w;
    }
    S[((size_t)((b * H_ + hh) * N_ + n)) * NPAD_ + m] = (half_t)fmaxf(accv, 1e-6f);
  }
}

// ---------------------------------------------------------------------------
// Deep-pipelined NT GEMM: 128x256 tile, BK=64, 8 waves (2M x 4N), triple-
// buffered LDS (144 KB), counted vmcnt(6) (T3+T4), st-swizzle (T2, rule #21:
// linear gload_lds dest + pre-swizzled global src + swizzled ds_read),
// setprio around MFMA clusters (T5).
//
// Pipeline invariants (race-free by construction):
//  - region r = kt%3; tile kt's units staged during tile kt-2's phases 0..2
//  - boundary wait at end of tile kt: vmcnt(6) leaves only tile kt+2's 6
//    loads in flight -> tile kt+1 fully landed (in-order retire, m135)
//  - region reuse (kt vs kt+3) separated by >=1 boundary vmcnt+barrier
//
// VARIANT 0: QKV (blockIdx.z selects input/weight/bias; z<2 bf16 row-major,
//            z==2 writes Vt[(bh*DK+d)*NPAD+n]).  VARIANT 1: f32 row-major.
// ---------------------------------------------------------------------------
template <int VARIANT>
__global__ __launch_bounds__(512, 1) void gemm8p(
    const bf16* __restrict__ A0, const bf16* __restrict__ A1, const bf16* __restrict__ A2,
    const bf16* __restrict__ W0, const bf16* __restrict__ W1, const bf16* __restrict__ W2,
    const float* __restrict__ b0, const float* __restrict__ b1, const float* __restrict__ b2,
    void* __restrict__ O0, void* __restrict__ O1, void* __restrict__ O2) {
  __shared__ bf16 Asb[3][128 * 64];   // 48 KB
  __shared__ bf16 Bsb[3][256 * 64];   // 96 KB

  const int z = (VARIANT == 0) ? blockIdx.z : 0;
  const bf16* A = (z == 0) ? A0 : (z == 1) ? A1 : A2;
  const bf16* W = (z == 0) ? W0 : (z == 1) ? W1 : W2;
  const float* bias = (z == 0) ? b0 : (z == 1) ? b1 : b2;

  const int tid = threadIdx.x;
  const int lane = tid & 63;
  const int wid = tid >> 6;
  const int l16 = lane & 15;
  const int quad = lane >> 4;
  const int wm = wid >> 2;   // 0..1 (M)
  const int wn = wid & 3;    // 0..3 (N)

  const bf16* gA = A + (size_t)blockIdx.y * 128 * D_;
  const bf16* gB = W + (size_t)blockIdx.x * 256 * D_;

  // staging: thread tid writes LDS linear bytes [unit + rr*8192 + tid*16).
  // That LDS slot (row = rr*64 + tid>>3, phys 16B-slot = tid&7) must hold
  // logical col-slot (tid&7)^(row&7) under the XOR swizzle -> pre-swizzle src.
  const int srow = tid >> 3;                       // 0..63
  const int lslot = (tid & 7) ^ (srow & 7);
  const size_t s0 = (size_t)srow * D_ + lslot * 8;
  const size_t s1 = (size_t)(64 + srow) * D_ + lslot * 8;
  const size_t s2 = (size_t)(128 + srow) * D_ + lslot * 8;
  const size_t s3 = (size_t)(192 + srow) * D_ + lslot * 8;

  // read offsets (elements): frag(row, kk) at row*64 + ((kk*4+quad)^(row&7))*8
  int arow[4], brow[4], kslot[2];
#pragma unroll
  for (int i = 0; i < 4; i++) arow[i] = (wm * 64 + i * 16 + l16) * 64;
#pragma unroll
  for (int j = 0; j < 4; j++) brow[j] = (wn * 64 + j * 16 + l16) * 64;
#pragma unroll
  for (int kk = 0; kk < 2; kk++) kslot[kk] = (((kk * 4 + quad) ^ (l16 & 7)) * 8);

  floatx4 acc[4][4];
#pragma unroll
  for (int i = 0; i < 4; i++)
#pragma unroll
    for (int j = 0; j < 4; j++)
#pragma unroll
      for (int r = 0; r < 4; r++) acc[i][j][r] = 0.0f;

  // ---- prologue: stage tiles 0 and 1 (regions 0,1); 12 loads in flight ----
#pragma unroll
  for (int kt = 0; kt < 2; kt++) {
    const bf16* sa = gA + kt * 64;
    const bf16* sb = gB + kt * 64;
    async_copy16(sa + s0, &Asb[kt][tid * 8]);
    async_copy16(sa + s1, &Asb[kt][4096 + tid * 8]);
    async_copy16(sb + s0, &Bsb[kt][tid * 8]);
    async_copy16(sb + s1, &Bsb[kt][4096 + tid * 8]);
    async_copy16(sb + s2, &Bsb[kt][8192 + tid * 8]);
    async_copy16(sb + s3, &Bsb[kt][12288 + tid * 8]);
  }
  WAITV6();   // tile 0 landed; tile 1's 6 loads still in flight
  BARRIER();

  // ---- main loop: 16 K-tiles x 4 phases ----
  for (int kt = 0; kt < KT_; ++kt) {
    const int g = kt % 3;
    const int gn = (kt + 2) % 3;
    const bool pf = (kt + 2 < KT_);
    const bf16* Ab = Asb[g];
    const bf16* Bb = Bsb[g];
    const bf16* pa = gA + (kt + 2) * 64;
    const bf16* pb = gB + (kt + 2) * 64;
    bf16x8 af[2][2], bfv[2][2];
#pragma unroll
    for (int ph = 0; ph < 4; ++ph) {
      const int ih = ph >> 1;
      const int jh = ph & 1;
      // ds-reads: A-frags held across the two jh phases of the same ih
      if (jh == 0) {
#pragma unroll
        for (int i2 = 0; i2 < 2; i2++)
#pragma unroll
          for (int kk = 0; kk < 2; kk++)
            af[i2][kk] = *(const bf16x8*)(Ab + arow[2 * ih + i2] + kslot[kk]);
      }
#pragma unroll
      for (int j2 = 0; j2 < 2; j2++)
#pragma unroll
        for (int kk = 0; kk < 2; kk++)
          bfv[j2][kk] = *(const bf16x8*)(Bb + brow[2 * jh + j2] + kslot[kk]);
      // stage one unit of tile kt+2 in phases 0,1,2
      if (pf) {
        if (ph == 0) {
          async_copy16(pa + s0, &Asb[gn][tid * 8]);
          async_copy16(pa + s1, &Asb[gn][4096 + tid * 8]);
        } else if (ph == 1) {
          async_copy16(pb + s0, &Bsb[gn][tid * 8]);
          async_copy16(pb + s1, &Bsb[gn][4096 + tid * 8]);
        } else if (ph == 2) {
          async_copy16(pb + s2, &Bsb[gn][8192 + tid * 8]);
          async_copy16(pb + s3, &Bsb[gn][12288 + tid * 8]);
        }
      }
      BARRIER();
      __builtin_amdgcn_s_setprio(1);
#pragma unroll
      for (int i2 = 0; i2 < 2; i2++)
#pragma unroll
        for (int j2 = 0; j2 < 2; j2++)
#pragma unroll
          for (int kk = 0; kk < 2; kk++)
            acc[2 * ih + i2][2 * jh + j2] = __builtin_amdgcn_mfma_f32_16x16x32_bf16(
                af[i2][kk], bfv[j2][kk], acc[2 * ih + i2][2 * jh + j2], 0, 0, 0);
      __builtin_amdgcn_s_setprio(0);
      if (ph == 3 && kt < KT_ - 1) {
        if (pf) WAITV6();   // next tile landed; tile kt+2's 6 loads may fly
        else    WAITV0();   // epilogue drain (last boundary only)
      }
      BARRIER();
    }
  }

  // ---- epilogue ----
  const int m0 = blockIdx.y * 128 + wm * 64;
  const int n0 = blockIdx.x * 256 + wn * 64;
#pragma unroll
  for (int j = 0; j < 4; j++) {
    const int col = n0 + j * 16 + l16;
    const float bv = bias[col];
#pragma unroll
    for (int i = 0; i < 4; i++) {
#pragma unroll
      for (int r = 0; r < 4; r++) {
        const int row = m0 + i * 16 + quad * 4 + r;
        float v = acc[i][j][r] + bv;
        if (VARIANT == 1) {
          ((float*)O0)[(size_t)row * D_ + col] = v;
        } else if (z < 2) {
          bf16* Cout = z ? (bf16*)O1 : (bf16*)O0;
          Cout[(size_t)row * D_ + col] = (bf16)v;
        } else {
          int b = row / N_;
          int n = row - b * N_;
          int h = col >> 7;
          int d = col & (DK_ - 1);
          ((bf16*)O2)[((size_t)((b * H_ + h) * DK_ + d)) * NPAD_ + n] = (bf16)v;
        }
      }
    }
  }
}

// ---------------------------------------------------------------------------
// Fused attention: per block = one (b,h) x 64 Q-rows.
// QK^T (S in regs, 14 j-frags) + LINEAR geo weight (multiplicative, f16) +
// softmax (shfl over 16-lane col groups) + P->LDS + PV -> AO.
// ---------------------------------------------------------------------------
__global__ __launch_bounds__(256) void attn_kernel(const bf16* __restrict__ Q,
                                                   const bf16* __restrict__ Kmat,
                                                   const bf16* __restrict__ Vt,
                                                   const half_t* __restrict__ Sb,
                                                   bf16* __restrict__ AO) {
  __shared__ bf16 Pl[4 * 16 * PSTRIDE_];

  const int f = blockIdx.x;
  const int tile = (f >> 3) & 3;
  const int bh = (f & 7) | ((f >> 5) << 3);      // tiles of one bh are 8 apart -> same XCD
  const int b = bh >> 3;
  const int h = bh & 7;
  const int wave = threadIdx.x >> 6;
  const int lane = threadIdx.x & 63;
  const int l16 = lane & 15;
  const int quad = lane >> 4;
  const int nrb = tile * 64 + wave * 16;

  // ---- QK^T ----
  floatx4 S[14];
#pragma unroll
  for (int j = 0; j < 14; j++)
#pragma unroll
    for (int r = 0; r < 4; r++) S[j][r] = 0.0f;

  const int na = nrb + l16;
  const bool nav = na < N_;
  const bf16* aptr = Q + ((size_t)(b * N_ + (nav ? na : 0))) * D_ + h * DK_ + quad * 8;
  bf16x8 afr[4];
#pragma unroll
  for (int kk = 0; kk < 4; kk++) afr[kk] = nav ? *(const bf16x8*)(aptr + kk * 32) : bzero8();

#pragma unroll
  for (int j = 0; j < 14; j++) {
    const int m = j * 16 + l16;
    const bool mv = m < N_;
    const bf16* kp = Kmat + ((size_t)(b * N_ + (mv ? m : 0))) * D_ + h * DK_ + quad * 8;
#pragma unroll
    for (int kk = 0; kk < 4; kk++) {
      bf16x8 bb = mv ? *(const bf16x8*)(kp + kk * 32) : bzero8();
      S[j] = __builtin_amdgcn_mfma_f32_16x16x32_bf16(afr[kk], bb, S[j], 0, 0, 0);
    }
  }

  // ---- scale + max + weighted exp + P->LDS ----
  const float scale = 0.08838834764831845f;  // 1/sqrt(128)
  const half_t* bbase = Sb + ((size_t)bh * N_) * NPAD_;
  bf16* pw = Pl + wave * 16 * PSTRIDE_;
  float inv[4];
#pragma unroll
  for (int r = 0; r < 4; r++) {
    const int n = nrb + quad * 4 + r;
    const size_t brow = (size_t)(n < N_ ? n : 0) * NPAD_;
    float mx = S[0][r] * scale;
#pragma unroll
    for (int j = 0; j < 14; j++) {
      S[j][r] *= scale;
      mx = fmaxf(mx, S[j][r]);
    }
#pragma unroll
    for (int off = 1; off < 16; off <<= 1) mx = fmaxf(mx, __shfl_xor(mx, off, 64));
    float sum = 0.0f;
#pragma unroll
    for (int j = 0; j < 14; j++) {
      const int m = j * 16 + l16;
      float w = (m < N_) ? (float)bbase[brow + m] : 0.0f;
      float e = w * __expf(S[j][r] - mx);
      sum += e;
      pw[(quad * 4 + r) * PSTRIDE_ + m] = (bf16)e;
    }
#pragma unroll
    for (int off = 1; off < 16; off <<= 1) sum += __shfl_xor(sum, off, 64);
    inv[r] = 1.0f / sum;
  }
  __syncthreads();

  // ---- PV ----
  floatx4 O[8];
#pragma unroll
  for (int j2 = 0; j2 < 8; j2++)
#pragma unroll
    for (int r = 0; r < 4; r++) O[j2][r] = 0.0f;

  const bf16* vbase = Vt + (size_t)bh * DK_ * NPAD_ + quad * 8;
  const bf16* pr = pw + l16 * PSTRIDE_ + quad * 8;
#pragma unroll
  for (int k0 = 0; k0 < NPAD_; k0 += 32) {
    bf16x8 a = *(const bf16x8*)(pr + k0);
#pragma unroll
    for (int j2 = 0; j2 < 8; j2++) {
      bf16x8 bb = *(const bf16x8*)(vbase + (size_t)(j2 * 16 + l16) * NPAD_ + k0);
      O[j2] = __builtin_amdgcn_mfma_f32_16x16x32_bf16(a, bb, O[j2], 0, 0, 0);
    }
  }

  // ---- epilogue: scale by 1/l, store ----
#pragma unroll
  for (int r = 0; r < 4; r++) {
    const int n = nrb + quad * 4 + r;
    if (n < N_) {
#pragma unroll
      for (int j2 = 0; j2 < 8; j2++) {
        AO[((size_t)(b * N_ + n)) * D_ + h * DK_ + j2 * 16 + l16] = (bf16)(O[j2][r] * inv[r]);
      }
    }
  }
}

// ---------------------------------------------------------------------------
extern "C" void kernel_launch(void* const* d_in, const int* in_sizes, int n_in,
                              void* d_out, int out_size, void* d_ws, size_t ws_size,
                              hipStream_t stream) {
  const float* xq = (const float*)d_in[0];
  const float* xk = (const float*)d_in[1];
  const float* xv = (const float*)d_in[2];
  const float* box = (const float*)d_in[3];
  const float* Wq = (const float*)d_in[4];
  const float* bq = (const float*)d_in[5];
  const float* Wk = (const float*)d_in[6];
  const float* bk = (const float*)d_in[7];
  const float* Wv = (const float*)d_in[8];
  const float* bv = (const float*)d_in[9];
  const float* Wo = (const float*)d_in[10];
  const float* bo = (const float*)d_in[11];
  const float* WGw = (const float*)d_in[12];
  const float* WGb = (const float*)d_in[13];

  size_t off = 0;
  char* wsc = (char*)d_ws;
  auto alloc = [&](size_t bytes) -> void* {
    void* p = wsc + off;
    off += (bytes + 255) & ~(size_t)255;
    return p;
  };
  bf16* xq_b = (bf16*)alloc((size_t)BN_ * D_ * 2);
  bf16* xk_b = (bf16*)alloc((size_t)BN_ * D_ * 2);
  bf16* xv_b = (bf16*)alloc((size_t)BN_ * D_ * 2);
  bf16* wq_b = (bf16*)alloc((size_t)D_ * D_ * 2);
  bf16* wk_b = (bf16*)alloc((size_t)D_ * D_ * 2);
  bf16* wv_b = (bf16*)alloc((size_t)D_ * D_ * 2);
  bf16* wo_b = (bf16*)alloc((size_t)D_ * D_ * 2);
  bf16* q_b = (bf16*)alloc((size_t)BN_ * D_ * 2);
  bf16* k_b = (bf16*)alloc((size_t)BN_ * D_ * 2);
  bf16* vt_b = (bf16*)alloc((size_t)BH_ * DK_ * NPAD_ * 2);
  bf16* ao_b = (bf16*)alloc((size_t)BN_ * D_ * 2);
  half_t* S = (half_t*)alloc((size_t)BH_ * N_ * NPAD_ * 2);

  const int n4x = BN_ * D_ / 4;
  const int n4w = D_ * D_ / 4;
  dim3 g3(n4x / 256, 3, 1);
  cvt3_kernel<<<g3, 256, 0, stream>>>(xq, xk, xv, xq_b, xk_b, xv_b, n4x);
  dim3 g4(n4w / 256, 4, 1);
  cvt4_kernel<<<g4, 256, 0, stream>>>(Wq, Wk, Wv, Wo, wq_b, wk_b, wv_b, wo_b, n4w);

  geo_kernel<<<(B_ * N_ * N_) / 256, 256, 0, stream>>>(box, WGw, WGb, S);

  // zero Vt so its pad columns (n in [196,224)) are 0, not poison
  hipMemsetAsync(vt_b, 0, (size_t)BH_ * DK_ * NPAD_ * 2, stream);

  dim3 gqkv(NTILE_, MT_, 3);
  gemm8p<0><<<gqkv, 512, 0, stream>>>(xq_b, xk_b, xv_b, wq_b, wk_b, wv_b, bq, bk, bv,
                                      q_b, k_b, vt_b);

  attn_kernel<<<1024, 256, 0, stream>>>(q_b, k_b, vt_b, S, ao_b);

  dim3 gout(NTILE_, MT_, 1);
  gemm8p<1><<<gout, 512, 0, stream>>>(ao_b, nullptr, nullptr, wo_b, nullptr, nullptr,
                                      bo, nullptr, nullptr, d_out, nullptr, nullptr);
}

// Round 5
// 355.651 us; speedup vs baseline: 1.0410x; 1.0410x over previous
//
#include <hip/hip_runtime.h>
#include <hip/hip_bf16.h>

typedef __bf16 bf16;
typedef _Float16 half_t;
typedef bf16 bf16x8 __attribute__((ext_vector_type(8)));
typedef bf16 bf16x4 __attribute__((ext_vector_type(4)));
typedef float floatx4 __attribute__((ext_vector_type(4)));

#define B_ 32
#define N_ 196
#define H_ 8
#define D_ 1024
#define DK_ 128
#define BN_ (B_ * N_)   // 6272
#define BH_ (B_ * H_)   // 256
#define NPAD_ 224       // padded N for S rows / Vt cols
#define PSTRIDE_ 232    // LDS P-tile col stride (16B aligned, bank-spread)

#define KT_ 16          // K tiles (BK=64), 1024 = 16*64 exact

typedef __attribute__((address_space(3))) unsigned int lds_uint;
typedef const __attribute__((address_space(1))) unsigned int glb_uint;

__device__ __forceinline__ void async_copy16(const bf16* g, bf16* l) {
  __builtin_amdgcn_global_load_lds((glb_uint*)g, (lds_uint*)l, 16, 0, 0);
}

__device__ __forceinline__ bf16x8 bzero8() {
  bf16x8 z;
#pragma unroll
  for (int i = 0; i < 8; i++) z[i] = (bf16)0.0f;
  return z;
}

#define BARRIER() asm volatile("s_barrier" ::: "memory")
#define WAITV0() asm volatile("s_waitcnt vmcnt(0)" ::: "memory")

// ---------------------------------------------------------------------------
// Batched f32 -> bf16 convert: blockIdx.y selects which tensor (same size).
// ---------------------------------------------------------------------------
__global__ __launch_bounds__(256) void cvt3_kernel(const float* __restrict__ s0,
                                                   const float* __restrict__ s1,
                                                   const float* __restrict__ s2,
                                                   bf16* __restrict__ d0,
                                                   bf16* __restrict__ d1,
                                                   bf16* __restrict__ d2, int n4) {
  const int which = blockIdx.y;
  const float* s = (which == 0) ? s0 : (which == 1) ? s1 : s2;
  bf16* d = (which == 0) ? d0 : (which == 1) ? d1 : d2;
  int i = blockIdx.x * 256 + threadIdx.x;
  if (i >= n4) return;
  float4 v = ((const float4*)s)[i];
  bf16x4 o;
  o[0] = (bf16)v.x;
  o[1] = (bf16)v.y;
  o[2] = (bf16)v.z;
  o[3] = (bf16)v.w;
  *(bf16x4*)(d + (size_t)i * 4) = o;
}

__global__ __launch_bounds__(256) void cvt4_kernel(const float* __restrict__ s0,
                                                   const float* __restrict__ s1,
                                                   const float* __restrict__ s2,
                                                   const float* __restrict__ s3,
                                                   bf16* __restrict__ d0,
                                                   bf16* __restrict__ d1,
                                                   bf16* __restrict__ d2,
                                                   bf16* __restrict__ d3, int n4) {
  const int which = blockIdx.y;
  const float* s = (which == 0) ? s0 : (which == 1) ? s1 : (which == 2) ? s2 : s3;
  bf16* d = (which == 0) ? d0 : (which == 1) ? d1 : (which == 2) ? d2 : d3;
  int i = blockIdx.x * 256 + threadIdx.x;
  if (i >= n4) return;
  float4 v = ((const float4*)s)[i];
  bf16x4 o;
  o[0] = (bf16)v.x;
  o[1] = (bf16)v.y;
  o[2] = (bf16)v.z;
  o[3] = (bf16)v.w;
  *(bf16x4*)(d + (size_t)i * 4) = o;
}

// ---------------------------------------------------------------------------
// Geometry weights (LINEAR domain): S[b,h,n,m] = max(relu(geo . WG_w[h] + b), 1e-6)
// stored f16. softmax(log w + s) == w*exp(s)/sum(w*exp(s)), so attn multiplies.
// ---------------------------------------------------------------------------
__global__ __launch_bounds__(256) void geo_kernel(const float* __restrict__ box,
                                                  const float* __restrict__ WGw,
                                                  const float* __restrict__ WGb,
                                                  half_t* __restrict__ S) {
  __shared__ float4 wsh[128];
  if (threadIdx.x < 128) wsh[threadIdx.x] = ((const float4*)WGw)[threadIdx.x];
  __syncthreads();

  int tid = blockIdx.x * 256 + threadIdx.x;
  int b = tid / (N_ * N_);
  int rem = tid - b * (N_ * N_);
  int n = rem / N_;
  int m = rem - n * N_;

  float4 bn = ((const float4*)box)[b * N_ + n];
  float4 bm = ((const float4*)box)[b * N_ + m];
  float cxn = (bn.x + bn.z) * 0.5f, cyn = (bn.y + bn.w) * 0.5f;
  float wn = bn.z - bn.x + 1.0f, hn = bn.w - bn.y + 1.0f;
  float cxm = (bm.x + bm.z) * 0.5f, cym = (bm.y + bm.w) * 0.5f;
  float wm = bm.z - bm.x + 1.0f, hm = bm.w - bm.y + 1.0f;

  float pos[4];
  pos[0] = __logf(fmaxf(fabsf((cxn - cxm) / wn), 1e-3f));
  pos[1] = __logf(fmaxf(fabsf((cyn - cym) / hn), 1e-3f));
  pos[2] = __logf(wn / wm);
  pos[3] = __logf(hn / hm);

  const float dims[8] = {1.0f,          0.4216965034f, 0.1778279410f, 0.0749894209f,
                         0.0316227766f, 0.0133352143f, 0.0056234133f, 0.0023713737f};
  float feat[64];
#pragma unroll
  for (int p = 0; p < 4; p++) {
#pragma unroll
    for (int f = 0; f < 8; f++) {
      float a = 100.0f * pos[p] * dims[f];
      feat[p * 8 + f] = __sinf(a);
      feat[32 + p * 8 + f] = __cosf(a);
    }
  }
#pragma unroll
  for (int hh = 0; hh < 8; hh++) {
    float accv = WGb[hh];
#pragma unroll
    for (int g4 = 0; g4 < 16; g4++) {
      float4 wv = wsh[hh * 16 + g4];
      accv += feat[g4 * 4 + 0] * wv.x + feat[g4 * 4 + 1] * wv.y +
              feat[g4 * 4 + 2] * wv.z + feat[g4 * 4 + 3] * wv.w;
    }
    S[((size_t)((b * H_ + hh) * N_ + n)) * NPAD_ + m] = (half_t)fmaxf(accv, 1e-6f);
  }
}

// ---------------------------------------------------------------------------
// 2-phase NT GEMM: 128x128 tile, BK=64, 4 waves (2M x 2N), per-wave 64x64,
// double-buffered LDS (64 KB -> 2 blocks/CU), 16-MFMA clusters, ONE
// barrier + ONE vmcnt(0) per K-tile.  XOR bank swizzle (conflict-free,
// verified round 2), setprio around MFMA clusters.
// Per K-tile/wave: 16 ds_read_b128 vs 32 MFMA (ratio 2.0, no redundant reads).
// Inter-block TLP (2 blocks/CU) covers the drain stall (m114 overlap).
//
// VARIANT 0: QKV (blockIdx.z selects input/weight/bias; z<2 bf16 row-major,
//            z==2 writes Vt[(bh*DK+d)*NPAD+n]).  VARIANT 1: f32 row-major.
// ---------------------------------------------------------------------------
template <int VARIANT>
__global__ __launch_bounds__(256, 2) void gemm2p(
    const bf16* __restrict__ A0, const bf16* __restrict__ A1, const bf16* __restrict__ A2,
    const bf16* __restrict__ W0, const bf16* __restrict__ W1, const bf16* __restrict__ W2,
    const float* __restrict__ b0, const float* __restrict__ b1, const float* __restrict__ b2,
    void* __restrict__ O0, void* __restrict__ O1, void* __restrict__ O2) {
  __shared__ bf16 As[2][128 * 64];   // 2 x 16 KB
  __shared__ bf16 Bs[2][128 * 64];   // 2 x 16 KB

  const int z = (VARIANT == 0) ? blockIdx.z : 0;
  const bf16* A = (z == 0) ? A0 : (z == 1) ? A1 : A2;
  const bf16* W = (z == 0) ? W0 : (z == 1) ? W1 : W2;
  const float* bias = (z == 0) ? b0 : (z == 1) ? b1 : b2;

  const int tid = threadIdx.x;
  const int lane = tid & 63;
  const int wid = tid >> 6;
  const int l16 = lane & 15;
  const int quad = lane >> 4;
  const int wm = wid >> 1;   // 0..1 (M half)
  const int wn = wid & 1;    // 0..1 (N half)

  const bf16* gA = A + (size_t)blockIdx.y * 128 * D_;
  const bf16* gB = W + (size_t)blockIdx.x * 128 * D_;

  // staging: thread tid writes 16B at LDS slot (u*256 + tid); row = slot>>3,
  // phys 16B-slot = tid&7 which holds logical slot (tid&7)^(row&7) under the
  // XOR swizzle -> pre-swizzled global source (rule #21: linear dest +
  // inverse-swizzled src + swizzled read).
  const int srow = tid >> 3;                        // 0..31
  const int lslot = (tid & 7) ^ (srow & 7);
  size_t sOff[4];
#pragma unroll
  for (int u = 0; u < 4; u++) sOff[u] = (size_t)(u * 32 + srow) * D_ + lslot * 8;

  // read offsets (elements): frag(row, kslot) at row*64 + ((kk*4+quad)^(row&7))*8
  int arow[4], brow[4], kslot[2];
#pragma unroll
  for (int i = 0; i < 4; i++) arow[i] = (wm * 64 + i * 16 + l16) * 64;
#pragma unroll
  for (int j = 0; j < 4; j++) brow[j] = (wn * 64 + j * 16 + l16) * 64;
#pragma unroll
  for (int kk = 0; kk < 2; kk++) kslot[kk] = ((kk * 4 + quad) ^ (l16 & 7)) * 8;

  floatx4 acc[4][4];
#pragma unroll
  for (int i = 0; i < 4; i++)
#pragma unroll
    for (int j = 0; j < 4; j++)
#pragma unroll
      for (int r = 0; r < 4; r++) acc[i][j][r] = 0.0f;

  // ---- prologue: stage tile 0 into buffer 0 ----
#pragma unroll
  for (int u = 0; u < 4; u++) {
    async_copy16(gA + sOff[u], &As[0][u * 2048 + tid * 8]);
    async_copy16(gB + sOff[u], &Bs[0][u * 2048 + tid * 8]);
  }
  WAITV0();
  BARRIER();

  // ---- main loop ----
  for (int kt = 0; kt < KT_; ++kt) {
    const int cur = kt & 1;
    const bf16* Ab = As[cur];
    const bf16* Bb = Bs[cur];
    const bool pf = (kt + 1 < KT_);
    const bf16* pa = gA + (kt + 1) * 64;
    const bf16* pb = gB + (kt + 1) * 64;
    bf16* dA = As[cur ^ 1];
    bf16* dB = Bs[cur ^ 1];
    bf16x8 af[4], bfv[4];

    // ---- phase 0 (kk=0): 8 ds_read + 4 A-stage + 16 MFMA ----
#pragma unroll
    for (int i = 0; i < 4; i++) af[i] = *(const bf16x8*)(Ab + arow[i] + kslot[0]);
#pragma unroll
    for (int j = 0; j < 4; j++) bfv[j] = *(const bf16x8*)(Bb + brow[j] + kslot[0]);
    if (pf) {
#pragma unroll
      for (int u = 0; u < 4; u++) async_copy16(pa + sOff[u], dA + u * 2048 + tid * 8);
    }
    __builtin_amdgcn_s_setprio(1);
#pragma unroll
    for (int i = 0; i < 4; i++)
#pragma unroll
      for (int j = 0; j < 4; j++)
        acc[i][j] = __builtin_amdgcn_mfma_f32_16x16x32_bf16(af[i], bfv[j], acc[i][j], 0, 0, 0);
    __builtin_amdgcn_s_setprio(0);

    // ---- phase 1 (kk=1): 8 ds_read + 4 B-stage + 16 MFMA ----
#pragma unroll
    for (int i = 0; i < 4; i++) af[i] = *(const bf16x8*)(Ab + arow[i] + kslot[1]);
#pragma unroll
    for (int j = 0; j < 4; j++) bfv[j] = *(const bf16x8*)(Bb + brow[j] + kslot[1]);
    if (pf) {
#pragma unroll
      for (int u = 0; u < 4; u++) async_copy16(pb + sOff[u], dB + u * 2048 + tid * 8);
    }
    __builtin_amdgcn_s_setprio(1);
#pragma unroll
    for (int i = 0; i < 4; i++)
#pragma unroll
      for (int j = 0; j < 4; j++)
        acc[i][j] = __builtin_amdgcn_mfma_f32_16x16x32_bf16(af[i], bfv[j], acc[i][j], 0, 0, 0);
    __builtin_amdgcn_s_setprio(0);

    // ---- tile boundary: drain next buffer's stage loads, sync ----
    if (pf) {
      WAITV0();
      BARRIER();
    }
  }

  // ---- epilogue ----
  const int m0 = blockIdx.y * 128 + wm * 64;
  const int n0 = blockIdx.x * 128 + wn * 64;
#pragma unroll
  for (int j = 0; j < 4; j++) {
    const int col = n0 + j * 16 + l16;
    const float bv = bias[col];
#pragma unroll
    for (int i = 0; i < 4; i++) {
#pragma unroll
      for (int r = 0; r < 4; r++) {
        const int row = m0 + i * 16 + quad * 4 + r;
        float v = acc[i][j][r] + bv;
        if (VARIANT == 1) {
          ((float*)O0)[(size_t)row * D_ + col] = v;
        } else if (z < 2) {
          bf16* Cout = z ? (bf16*)O1 : (bf16*)O0;
          Cout[(size_t)row * D_ + col] = (bf16)v;
        } else {
          int b = row / N_;
          int n = row - b * N_;
          int h = col >> 7;
          int d = col & (DK_ - 1);
          ((bf16*)O2)[((size_t)((b * H_ + h) * DK_ + d)) * NPAD_ + n] = (bf16)v;
        }
      }
    }
  }
}

// ---------------------------------------------------------------------------
// Fused attention: per block = one (b,h) x 64 Q-rows.
// QK^T (S in regs, 14 j-frags) + LINEAR geo weight (multiplicative, f16) +
// softmax (shfl over 16-lane col groups) + P->LDS + PV -> AO.
// ---------------------------------------------------------------------------
__global__ __launch_bounds__(256) void attn_kernel(const bf16* __restrict__ Q,
                                                   const bf16* __restrict__ Kmat,
                                                   const bf16* __restrict__ Vt,
                                                   const half_t* __restrict__ Sb,
                                                   bf16* __restrict__ AO) {
  __shared__ bf16 Pl[4 * 16 * PSTRIDE_];

  const int f = blockIdx.x;
  const int tile = (f >> 3) & 3;
  const int bh = (f & 7) | ((f >> 5) << 3);      // tiles of one bh are 8 apart -> same XCD
  const int b = bh >> 3;
  const int h = bh & 7;
  const int wave = threadIdx.x >> 6;
  const int lane = threadIdx.x & 63;
  const int l16 = lane & 15;
  const int quad = lane >> 4;
  const int nrb = tile * 64 + wave * 16;

  // ---- QK^T ----
  floatx4 S[14];
#pragma unroll
  for (int j = 0; j < 14; j++)
#pragma unroll
    for (int r = 0; r < 4; r++) S[j][r] = 0.0f;

  const int na = nrb + l16;
  const bool nav = na < N_;
  const bf16* aptr = Q + ((size_t)(b * N_ + (nav ? na : 0))) * D_ + h * DK_ + quad * 8;
  bf16x8 afr[4];
#pragma unroll
  for (int kk = 0; kk < 4; kk++) afr[kk] = nav ? *(const bf16x8*)(aptr + kk * 32) : bzero8();

#pragma unroll
  for (int j = 0; j < 14; j++) {
    const int m = j * 16 + l16;
    const bool mv = m < N_;
    const bf16* kp = Kmat + ((size_t)(b * N_ + (mv ? m : 0))) * D_ + h * DK_ + quad * 8;
#pragma unroll
    for (int kk = 0; kk < 4; kk++) {
      bf16x8 bb = mv ? *(const bf16x8*)(kp + kk * 32) : bzero8();
      __builtin_amdgcn_s_setprio(1);
      S[j] = __builtin_amdgcn_mfma_f32_16x16x32_bf16(afr[kk], bb, S[j], 0, 0, 0);
      __builtin_amdgcn_s_setprio(0);
    }
  }

  // ---- scale + max + weighted exp + P->LDS ----
  const float scale = 0.08838834764831845f;  // 1/sqrt(128)
  const half_t* bbase = Sb + ((size_t)bh * N_) * NPAD_;
  bf16* pw = Pl + wave * 16 * PSTRIDE_;
  float inv[4];
#pragma unroll
  for (int r = 0; r < 4; r++) {
    const int n = nrb + quad * 4 + r;
    const size_t brow = (size_t)(n < N_ ? n : 0) * NPAD_;
    float mx = S[0][r] * scale;
#pragma unroll
    for (int j = 0; j < 14; j++) {
      S[j][r] *= scale;
      mx = fmaxf(mx, S[j][r]);
    }
#pragma unroll
    for (int off = 1; off < 16; off <<= 1) mx = fmaxf(mx, __shfl_xor(mx, off, 64));
    float sum = 0.0f;
#pragma unroll
    for (int j = 0; j < 14; j++) {
      const int m = j * 16 + l16;
      float w = (m < N_) ? (float)bbase[brow + m] : 0.0f;
      float e = w * __expf(S[j][r] - mx);
      sum += e;
      pw[(quad * 4 + r) * PSTRIDE_ + m] = (bf16)e;
    }
#pragma unroll
    for (int off = 1; off < 16; off <<= 1) sum += __shfl_xor(sum, off, 64);
    inv[r] = 1.0f / sum;
  }
  __syncthreads();

  // ---- PV ----
  floatx4 O[8];
#pragma unroll
  for (int j2 = 0; j2 < 8; j2++)
#pragma unroll
    for (int r = 0; r < 4; r++) O[j2][r] = 0.0f;

  const bf16* vbase = Vt + (size_t)bh * DK_ * NPAD_ + quad * 8;
  const bf16* pr = pw + l16 * PSTRIDE_ + quad * 8;
#pragma unroll
  for (int k0 = 0; k0 < NPAD_; k0 += 32) {
    bf16x8 a = *(const bf16x8*)(pr + k0);
#pragma unroll
    for (int j2 = 0; j2 < 8; j2++) {
      bf16x8 bb = *(const bf16x8*)(vbase + (size_t)(j2 * 16 + l16) * NPAD_ + k0);
      __builtin_amdgcn_s_setprio(1);
      O[j2] = __builtin_amdgcn_mfma_f32_16x16x32_bf16(a, bb, O[j2], 0, 0, 0);
      __builtin_amdgcn_s_setprio(0);
    }
  }

  // ---- epilogue: scale by 1/l, store ----
#pragma unroll
  for (int r = 0; r < 4; r++) {
    const int n = nrb + quad * 4 + r;
    if (n < N_) {
#pragma unroll
      for (int j2 = 0; j2 < 8; j2++) {
        AO[((size_t)(b * N_ + n)) * D_ + h * DK_ + j2 * 16 + l16] = (bf16)(O[j2][r] * inv[r]);
      }
    }
  }
}

// ---------------------------------------------------------------------------
extern "C" void kernel_launch(void* const* d_in, const int* in_sizes, int n_in,
                              void* d_out, int out_size, void* d_ws, size_t ws_size,
                              hipStream_t stream) {
  const float* xq = (const float*)d_in[0];
  const float* xk = (const float*)d_in[1];
  const float* xv = (const float*)d_in[2];
  const float* box = (const float*)d_in[3];
  const float* Wq = (const float*)d_in[4];
  const float* bq = (const float*)d_in[5];
  const float* Wk = (const float*)d_in[6];
  const float* bk = (const float*)d_in[7];
  const float* Wv = (const float*)d_in[8];
  const float* bv = (const float*)d_in[9];
  const float* Wo = (const float*)d_in[10];
  const float* bo = (const float*)d_in[11];
  const float* WGw = (const float*)d_in[12];
  const float* WGb = (const float*)d_in[13];

  size_t off = 0;
  char* wsc = (char*)d_ws;
  auto alloc = [&](size_t bytes) -> void* {
    void* p = wsc + off;
    off += (bytes + 255) & ~(size_t)255;
    return p;
  };
  bf16* xq_b = (bf16*)alloc((size_t)BN_ * D_ * 2);
  bf16* xk_b = (bf16*)alloc((size_t)BN_ * D_ * 2);
  bf16* xv_b = (bf16*)alloc((size_t)BN_ * D_ * 2);
  bf16* wq_b = (bf16*)alloc((size_t)D_ * D_ * 2);
  bf16* wk_b = (bf16*)alloc((size_t)D_ * D_ * 2);
  bf16* wv_b = (bf16*)alloc((size_t)D_ * D_ * 2);
  bf16* wo_b = (bf16*)alloc((size_t)D_ * D_ * 2);
  bf16* q_b = (bf16*)alloc((size_t)BN_ * D_ * 2);
  bf16* k_b = (bf16*)alloc((size_t)BN_ * D_ * 2);
  bf16* vt_b = (bf16*)alloc((size_t)BH_ * DK_ * NPAD_ * 2);
  bf16* ao_b = (bf16*)alloc((size_t)BN_ * D_ * 2);
  half_t* S = (half_t*)alloc((size_t)BH_ * N_ * NPAD_ * 2);

  const int n4x = BN_ * D_ / 4;
  const int n4w = D_ * D_ / 4;
  dim3 g3(n4x / 256, 3, 1);
  cvt3_kernel<<<g3, 256, 0, stream>>>(xq, xk, xv, xq_b, xk_b, xv_b, n4x);
  dim3 g4(n4w / 256, 4, 1);
  cvt4_kernel<<<g4, 256, 0, stream>>>(Wq, Wk, Wv, Wo, wq_b, wk_b, wv_b, wo_b, n4w);

  geo_kernel<<<(B_ * N_ * N_) / 256, 256, 0, stream>>>(box, WGw, WGb, S);

  // zero Vt so its pad columns (n in [196,224)) are 0, not poison
  hipMemsetAsync(vt_b, 0, (size_t)BH_ * DK_ * NPAD_ * 2, stream);

  dim3 gqkv(D_ / 128, BN_ / 128, 3);
  gemm2p<0><<<gqkv, 256, 0, stream>>>(xq_b, xk_b, xv_b, wq_b, wk_b, wv_b, bq, bk, bv,
                                      q_b, k_b, vt_b);

  attn_kernel<<<1024, 256, 0, stream>>>(q_b, k_b, vt_b, S, ao_b);

  dim3 gout(D_ / 128, BN_ / 128, 1);
  gemm2p<1><<<gout, 256, 0, stream>>>(ao_b, nullptr, nullptr, wo_b, nullptr, nullptr,
                                      bo, nullptr, nullptr, d_out, nullptr, nullptr);
}

// Round 6
// 320.045 us; speedup vs baseline: 1.1568x; 1.1113x over previous
//
#include <hip/hip_runtime.h>
#include <hip/hip_bf16.h>

typedef __bf16 bf16;
typedef _Float16 half_t;
typedef bf16 bf16x8 __attribute__((ext_vector_type(8)));
typedef bf16 bf16x4 __attribute__((ext_vector_type(4)));
typedef float floatx4 __attribute__((ext_vector_type(4)));

#define B_ 32
#define N_ 196
#define H_ 8
#define D_ 1024
#define DK_ 128
#define BN_ (B_ * N_)   // 6272
#define BH_ (B_ * H_)   // 256
#define NPAD_ 224       // padded N for S rows / Vt cols
#define PSTRIDE_ 232    // LDS P-tile col stride (16B aligned, bank-spread)

#define KT3_ 32         // K tiles (BK=32), 1024 = 32*32 exact

typedef __attribute__((address_space(3))) unsigned int lds_uint;
typedef const __attribute__((address_space(1))) unsigned int glb_uint;

__device__ __forceinline__ void async_copy16(const bf16* g, bf16* l) {
  __builtin_amdgcn_global_load_lds((glb_uint*)g, (lds_uint*)l, 16, 0, 0);
}

#define BARRIER() asm volatile("s_barrier" ::: "memory")
#define WAITV0() asm volatile("s_waitcnt vmcnt(0)" ::: "memory")
#define WAITV4() asm volatile("s_waitcnt vmcnt(4)" ::: "memory")

// ---------------------------------------------------------------------------
// Batched f32 -> bf16 convert: blockIdx.y selects which tensor (same size).
// ---------------------------------------------------------------------------
__global__ __launch_bounds__(256) void cvt3_kernel(const float* __restrict__ s0,
                                                   const float* __restrict__ s1,
                                                   const float* __restrict__ s2,
                                                   bf16* __restrict__ d0,
                                                   bf16* __restrict__ d1,
                                                   bf16* __restrict__ d2, int n4) {
  const int which = blockIdx.y;
  const float* s = (which == 0) ? s0 : (which == 1) ? s1 : s2;
  bf16* d = (which == 0) ? d0 : (which == 1) ? d1 : d2;
  int i = blockIdx.x * 256 + threadIdx.x;
  if (i >= n4) return;
  float4 v = ((const float4*)s)[i];
  bf16x4 o;
  o[0] = (bf16)v.x;
  o[1] = (bf16)v.y;
  o[2] = (bf16)v.z;
  o[3] = (bf16)v.w;
  *(bf16x4*)(d + (size_t)i * 4) = o;
}

__global__ __launch_bounds__(256) void cvt4_kernel(const float* __restrict__ s0,
                                                   const float* __restrict__ s1,
                                                   const float* __restrict__ s2,
                                                   const float* __restrict__ s3,
                                                   bf16* __restrict__ d0,
                                                   bf16* __restrict__ d1,
                                                   bf16* __restrict__ d2,
                                                   bf16* __restrict__ d3, int n4) {
  const int which = blockIdx.y;
  const float* s = (which == 0) ? s0 : (which == 1) ? s1 : (which == 2) ? s2 : s3;
  bf16* d = (which == 0) ? d0 : (which == 1) ? d1 : (which == 2) ? d2 : d3;
  int i = blockIdx.x * 256 + threadIdx.x;
  if (i >= n4) return;
  float4 v = ((const float4*)s)[i];
  bf16x4 o;
  o[0] = (bf16)v.x;
  o[1] = (bf16)v.y;
  o[2] = (bf16)v.z;
  o[3] = (bf16)v.w;
  *(bf16x4*)(d + (size_t)i * 4) = o;
}

// ---------------------------------------------------------------------------
// Geometry weights (LINEAR domain): S[b,h,n,m] = max(relu(geo . WG_w[h] + b), 1e-6)
// stored f16. softmax(log w + s) == w*exp(s)/sum(w*exp(s)), so attn multiplies.
// ---------------------------------------------------------------------------
__global__ __launch_bounds__(256) void geo_kernel(const float* __restrict__ box,
                                                  const float* __restrict__ WGw,
                                                  const float* __restrict__ WGb,
                                                  half_t* __restrict__ S) {
  __shared__ float4 wsh[128];
  if (threadIdx.x < 128) wsh[threadIdx.x] = ((const float4*)WGw)[threadIdx.x];
  __syncthreads();

  int tid = blockIdx.x * 256 + threadIdx.x;
  int b = tid / (N_ * N_);
  int rem = tid - b * (N_ * N_);
  int n = rem / N_;
  int m = rem - n * N_;

  float4 bn = ((const float4*)box)[b * N_ + n];
  float4 bm = ((const float4*)box)[b * N_ + m];
  float cxn = (bn.x + bn.z) * 0.5f, cyn = (bn.y + bn.w) * 0.5f;
  float wn = bn.z - bn.x + 1.0f, hn = bn.w - bn.y + 1.0f;
  float cxm = (bm.x + bm.z) * 0.5f, cym = (bm.y + bm.w) * 0.5f;
  float wm = bm.z - bm.x + 1.0f, hm = bm.w - bm.y + 1.0f;

  float pos[4];
  pos[0] = __logf(fmaxf(fabsf((cxn - cxm) / wn), 1e-3f));
  pos[1] = __logf(fmaxf(fabsf((cyn - cym) / hn), 1e-3f));
  pos[2] = __logf(wn / wm);
  pos[3] = __logf(hn / hm);

  const float dims[8] = {1.0f,          0.4216965034f, 0.1778279410f, 0.0749894209f,
                         0.0316227766f, 0.0133352143f, 0.0056234133f, 0.0023713737f};
  float feat[64];
#pragma unroll
  for (int p = 0; p < 4; p++) {
#pragma unroll
    for (int f = 0; f < 8; f++) {
      float a = 100.0f * pos[p] * dims[f];
      feat[p * 8 + f] = __sinf(a);
      feat[32 + p * 8 + f] = __cosf(a);
    }
  }
#pragma unroll
  for (int hh = 0; hh < 8; hh++) {
    float accv = WGb[hh];
#pragma unroll
    for (int g4 = 0; g4 < 16; g4++) {
      float4 wv = wsh[hh * 16 + g4];
      accv += feat[g4 * 4 + 0] * wv.x + feat[g4 * 4 + 1] * wv.y +
              feat[g4 * 4 + 2] * wv.z + feat[g4 * 4 + 3] * wv.w;
    }
    S[((size_t)((b * H_ + hh) * N_ + n)) * NPAD_ + m] = (half_t)fmaxf(accv, 1e-6f);
  }
}

// ---------------------------------------------------------------------------
// Counted-vmcnt NT GEMM: 128x128 tile, BK=32, 4 waves (2M x 2N), per-wave
// 64x64, TRIPLE-buffered LDS (48 KB -> 3 blocks/CU), 2-tiles-ahead prefetch,
// boundary wait vmcnt(4) (never 0 until the tail).  XOR bank swizzle
// (conflict-free, verified), setprio around the 16-MFMA cluster.
//
// Pipeline invariants (race-free by construction):
//  - iter kt computes region kt%3, stages tile kt+2 into region (kt+2)%3
//    == (kt-1)%3, whose readers all crossed the previous boundary barrier.
//  - boundary wait vmcnt(4): outstanding = kt+1's 4 + kt+2's 4; in-order
//    retirement (m135) -> kt+1 landed, kt+2's 4 still flying.
//
// VARIANT 0: QKV (blockIdx.z selects input/weight/bias; z<2 bf16 row-major,
//            z==2 writes Vt[(bh*DK+d)*NPAD+n]).  VARIANT 1: f32 row-major.
// ---------------------------------------------------------------------------
template <int VARIANT>
__global__ __launch_bounds__(256, 3) void gemm3b(
    const bf16* __restrict__ A0, const bf16* __restrict__ A1, const bf16* __restrict__ A2,
    const bf16* __restrict__ W0, const bf16* __restrict__ W1, const bf16* __restrict__ W2,
    const float* __restrict__ b0, const float* __restrict__ b1, const float* __restrict__ b2,
    void* __restrict__ O0, void* __restrict__ O1, void* __restrict__ O2) {
  __shared__ bf16 As[3][128 * 32];   // 3 x 8 KB
  __shared__ bf16 Bs[3][128 * 32];   // 3 x 8 KB

  const int z = (VARIANT == 0) ? blockIdx.z : 0;
  const bf16* A = (z == 0) ? A0 : (z == 1) ? A1 : A2;
  const bf16* W = (z == 0) ? W0 : (z == 1) ? W1 : W2;
  const float* bias = (z == 0) ? b0 : (z == 1) ? b1 : b2;

  const int tid = threadIdx.x;
  const int lane = tid & 63;
  const int wid = tid >> 6;
  const int l16 = lane & 15;
  const int quad = lane >> 4;
  const int wm = wid >> 1;   // 0..1 (M half)
  const int wn = wid & 1;    // 0..1 (N half)

  const bf16* gA = A + (size_t)blockIdx.y * 128 * D_;
  const bf16* gB = W + (size_t)blockIdx.x * 128 * D_;

  // staging: 512 units of 16B per tile; 2 units/thread.  Row = slot>>2
  // (4 col-slots of 8 bf16 per row), phys col-slot = slot&3 holds logical
  // (slot&3)^(row&3) -> pre-swizzled global source, linear LDS dest.
  size_t sOff[2];
  int sDst[2];
#pragma unroll
  for (int u = 0; u < 2; u++) {
    const int slot = u * 256 + tid;
    const int srow = slot >> 2;
    const int scs = slot & 3;
    sOff[u] = (size_t)srow * D_ + (size_t)((scs ^ (srow & 3)) * 8);
    sDst[u] = slot * 8;
  }

  // read offsets (elements): frag at row rr -> rr*32 + ((quad^(rr&3))*8)
  int arow[4], brow[4];
#pragma unroll
  for (int i = 0; i < 4; i++) arow[i] = (wm * 64 + i * 16 + l16) * 32;
#pragma unroll
  for (int j = 0; j < 4; j++) brow[j] = (wn * 64 + j * 16 + l16) * 32;
  const int kslot = (quad ^ (l16 & 3)) * 8;

  floatx4 acc[4][4];
#pragma unroll
  for (int i = 0; i < 4; i++)
#pragma unroll
    for (int j = 0; j < 4; j++)
#pragma unroll
      for (int r = 0; r < 4; r++) acc[i][j][r] = 0.0f;

  // ---- prologue: stage tiles 0 and 1 into regions 0 and 1 ----
#pragma unroll
  for (int kt = 0; kt < 2; kt++) {
    const bf16* sa = gA + kt * 32;
    const bf16* sb = gB + kt * 32;
#pragma unroll
    for (int u = 0; u < 2; u++) {
      async_copy16(sa + sOff[u], &As[kt][sDst[u]]);
      async_copy16(sb + sOff[u], &Bs[kt][sDst[u]]);
    }
  }
  WAITV4();   // tile 0 landed; tile 1's 4 loads still in flight
  BARRIER();

  // ---- main loop: 32 K-tiles, one 16-MFMA phase each ----
  for (int kt = 0; kt < KT3_; ++kt) {
    const int g = kt % 3;
    const bool pf = (kt + 2 < KT3_);
    if (pf) {
      const int gn = (kt + 2) % 3;
      const bf16* pa = gA + (kt + 2) * 32;
      const bf16* pb = gB + (kt + 2) * 32;
#pragma unroll
      for (int u = 0; u < 2; u++) {
        async_copy16(pa + sOff[u], &As[gn][sDst[u]]);
        async_copy16(pb + sOff[u], &Bs[gn][sDst[u]]);
      }
    }
    const bf16* Ab = As[g];
    const bf16* Bb = Bs[g];
    bf16x8 af[4], bfv[4];
#pragma unroll
    for (int i = 0; i < 4; i++) af[i] = *(const bf16x8*)(Ab + arow[i] + kslot);
#pragma unroll
    for (int j = 0; j < 4; j++) bfv[j] = *(const bf16x8*)(Bb + brow[j] + kslot);
    __builtin_amdgcn_s_setprio(1);
#pragma unroll
    for (int i = 0; i < 4; i++)
#pragma unroll
      for (int j = 0; j < 4; j++)
        acc[i][j] = __builtin_amdgcn_mfma_f32_16x16x32_bf16(af[i], bfv[j], acc[i][j], 0, 0, 0);
    __builtin_amdgcn_s_setprio(0);
    if (kt < KT3_ - 1) {
      if (pf) WAITV4();   // kt+1 landed; kt+2's 4 loads may fly
      else    WAITV0();   // tail drain (last boundary only)
      BARRIER();
    }
  }

  // ---- epilogue ----
  const int m0 = blockIdx.y * 128 + wm * 64;
  const int n0 = blockIdx.x * 128 + wn * 64;
#pragma unroll
  for (int j = 0; j < 4; j++) {
    const int col = n0 + j * 16 + l16;
    const float bv = bias[col];
#pragma unroll
    for (int i = 0; i < 4; i++) {
#pragma unroll
      for (int r = 0; r < 4; r++) {
        const int row = m0 + i * 16 + quad * 4 + r;
        float v = acc[i][j][r] + bv;
        if (VARIANT == 1) {
          ((float*)O0)[(size_t)row * D_ + col] = v;
        } else if (z < 2) {
          bf16* Cout = z ? (bf16*)O1 : (bf16*)O0;
          Cout[(size_t)row * D_ + col] = (bf16)v;
        } else {
          int b = row / N_;
          int n = row - b * N_;
          int h = col >> 7;
          int d = col & (DK_ - 1);
          ((bf16*)O2)[((size_t)((b * H_ + h) * DK_ + d)) * NPAD_ + n] = (bf16)v;
        }
      }
    }
  }
}

// ---------------------------------------------------------------------------
// Fused attention: per block = one (b,h) x 64 Q-rows.
// K and V staged into LDS (coalesced global_load_lds, dbuf 32-row/32-col
// tiles, XOR swizzle).  K-LDS is unioned with the P-tile (phases disjoint,
// barrier between).  QK^T + LINEAR geo weight (f16, multiplicative) +
// softmax + P->LDS + PV -> AO.
// ---------------------------------------------------------------------------
__global__ __launch_bounds__(256) void attn_kernel(const bf16* __restrict__ Q,
                                                   const bf16* __restrict__ Kmat,
                                                   const bf16* __restrict__ Vt,
                                                   const half_t* __restrict__ Sb,
                                                   bf16* __restrict__ AO) {
  // smem layout: [0, 29696) = Pl (4*16*PSTRIDE_ bf16) UNION Ks[2][32*128];
  //              [29696, 46080) = Vs[2][128*32]
  __shared__ alignas(16) char smem[46080];
  bf16* KsB[2] = {(bf16*)smem, (bf16*)smem + 4096};
  bf16* Pl = (bf16*)smem;
  bf16* VsB[2] = {(bf16*)(smem + 29696), (bf16*)(smem + 29696) + 4096};

  const int f = blockIdx.x;
  const int tile = (f >> 3) & 3;
  const int bh = (f & 7) | ((f >> 5) << 3);      // tiles of one bh are 8 apart -> same XCD
  const int b = bh >> 3;
  const int h = bh & 7;
  const int tid = threadIdx.x;
  const int wave = tid >> 6;
  const int lane = tid & 63;
  const int l16 = lane & 15;
  const int quad = lane >> 4;
  const int nrb = tile * 64 + wave * 16;

  // K staging offsets: 512 units of 16B per 32x128 tile; 2 units/thread.
  // row = slot>>4 (16 col-slots/row), phys col-slot = slot&15 holds logical
  // (slot&15)^(row&7) -> pre-swizzled source.
  size_t kSrc[2];
  int kDst[2];
#pragma unroll
  for (int u = 0; u < 2; u++) {
    const int slot = u * 256 + tid;
    const int srow = slot >> 4;
    const int scs = slot & 15;
    kSrc[u] = (size_t)(b * N_ + srow) * D_ + h * DK_ + (scs ^ (srow & 7)) * 8;
    kDst[u] = slot * 8;
  }
  // V staging offsets: 512 units per 128x32 tile (of Vt[d][n]); row = slot>>2,
  // phys col-slot = slot&3 holds logical (slot&3)^(row&3).
  size_t vSrc[2];
#pragma unroll
  for (int u = 0; u < 2; u++) {
    const int slot = u * 256 + tid;
    const int vrow = slot >> 2;
    const int vcs = slot & 3;
    vSrc[u] = (size_t)bh * DK_ * NPAD_ + (size_t)vrow * NPAD_ + (vcs ^ (vrow & 3)) * 8;
  }

  // ---- prologue: stage K tile 0; load Q fragments ----
#pragma unroll
  for (int u = 0; u < 2; u++) async_copy16(Kmat + kSrc[u], KsB[0] + kDst[u]);

  const int na = nrb + l16;
  const bool nav = na < N_;
  const bf16* aptr = Q + ((size_t)(b * N_ + (nav ? na : 0))) * D_ + h * DK_ + quad * 8;
  bf16x8 afr[4];
#pragma unroll
  for (int kk = 0; kk < 4; kk++) {
    bf16x8 v = *(const bf16x8*)(aptr + kk * 32);
    if (!nav) {
#pragma unroll
      for (int e = 0; e < 8; e++) v[e] = (bf16)0.0f;
    }
    afr[kk] = v;
  }
  WAITV0();
  BARRIER();

  // ---- QK^T over 7 K-tiles of 32 rows (dbuf) ----
  floatx4 S[14];
#pragma unroll
  for (int j = 0; j < 14; j++)
#pragma unroll
    for (int r = 0; r < 4; r++) S[j][r] = 0.0f;

  for (int jt = 0; jt < 7; ++jt) {
    const int cur = jt & 1;
    if (jt < 6) {
      const size_t koff = (size_t)((jt + 1) * 32) * D_;
#pragma unroll
      for (int u = 0; u < 2; u++)
        async_copy16(Kmat + kSrc[u] + koff, KsB[cur ^ 1] + kDst[u]);
    }
    const bf16* Kb = KsB[cur];
    __builtin_amdgcn_s_setprio(1);
#pragma unroll
    for (int jj = 0; jj < 2; jj++) {
      const int mloc = jj * 16 + l16;
#pragma unroll
      for (int kk = 0; kk < 4; kk++) {
        bf16x8 bb = *(const bf16x8*)(Kb + mloc * 128 + ((kk * 4 + quad) ^ (l16 & 7)) * 8);
        S[jt * 2 + jj] = __builtin_amdgcn_mfma_f32_16x16x32_bf16(afr[kk], bb, S[jt * 2 + jj], 0, 0, 0);
      }
    }
    __builtin_amdgcn_s_setprio(0);
    if (jt < 6) {
      WAITV0();
      BARRIER();
    }
  }

  // early V-tile-0 stage (overlaps softmax; lands by the __syncthreads drain)
#pragma unroll
  for (int u = 0; u < 2; u++) async_copy16(Vt + vSrc[u], VsB[0] + kDst[u]);

  // all waves done reading Ks before Pl (same LDS region) is written
  BARRIER();

  // ---- scale + mask + max + weighted exp + P->LDS ----
  const float scale = 0.08838834764831845f;  // 1/sqrt(128)
  const half_t* bbase = Sb + ((size_t)bh * N_) * NPAD_;
  bf16* pw = Pl + wave * 16 * PSTRIDE_;
  float inv[4];
#pragma unroll
  for (int r = 0; r < 4; r++) {
    const int n = nrb + quad * 4 + r;
    const bool nv = n < N_;
    const size_t brow = (size_t)(nv ? n : 0) * NPAD_;
    float mx = -1e30f;
#pragma unroll
    for (int j = 0; j < 14; j++) {
      const int m = j * 16 + l16;
      // mask pad rows/cols BEFORE the max: staged K rows >=196 are garbage
      float s = (nv && m < N_) ? S[j][r] * scale : -1e30f;
      S[j][r] = s;
      mx = fmaxf(mx, s);
    }
#pragma unroll
    for (int off = 1; off < 16; off <<= 1) mx = fmaxf(mx, __shfl_xor(mx, off, 64));
    float sum = 0.0f;
#pragma unroll
    for (int j = 0; j < 14; j++) {
      const int m = j * 16 + l16;
      float w = (m < N_) ? (float)bbase[brow + m] : 0.0f;
      float e = w * __expf(S[j][r] - mx);
      sum += e;
      pw[(quad * 4 + r) * PSTRIDE_ + m] = (bf16)e;
    }
#pragma unroll
    for (int off = 1; off < 16; off <<= 1) sum += __shfl_xor(sum, off, 64);
    inv[r] = 1.0f / sum;
  }
  __syncthreads();   // drains vmcnt too: V tile 0 landed, P visible

  // ---- PV over 7 n-tiles of 32 cols (dbuf) ----
  floatx4 O[8];
#pragma unroll
  for (int j2 = 0; j2 < 8; j2++)
#pragma unroll
    for (int r = 0; r < 4; r++) O[j2][r] = 0.0f;

  const bf16* pr = pw + l16 * PSTRIDE_ + quad * 8;
  for (int t7 = 0; t7 < 7; ++t7) {
    const int cur = t7 & 1;
    if (t7 < 6) {
      const size_t voff = (size_t)((t7 + 1) * 32);
#pragma unroll
      for (int u = 0; u < 2; u++)
        async_copy16(Vt + vSrc[u] + voff, VsB[cur ^ 1] + kDst[u]);
    }
    const bf16* Vb = VsB[cur];
    bf16x8 a = *(const bf16x8*)(pr + t7 * 32);
    __builtin_amdgcn_s_setprio(1);
#pragma unroll
    for (int j2 = 0; j2 < 8; j2++) {
      bf16x8 bb = *(const bf16x8*)(Vb + (j2 * 16 + l16) * 32 + (quad ^ (l16 & 3)) * 8);
      O[j2] = __builtin_amdgcn_mfma_f32_16x16x32_bf16(a, bb, O[j2], 0, 0, 0);
    }
    __builtin_amdgcn_s_setprio(0);
    if (t7 < 6) {
      WAITV0();
      BARRIER();
    }
  }

  // ---- epilogue: scale by 1/l, store ----
#pragma unroll
  for (int r = 0; r < 4; r++) {
    const int n = nrb + quad * 4 + r;
    if (n < N_) {
#pragma unroll
      for (int j2 = 0; j2 < 8; j2++) {
        AO[((size_t)(b * N_ + n)) * D_ + h * DK_ + j2 * 16 + l16] = (bf16)(O[j2][r] * inv[r]);
      }
    }
  }
}

// ---------------------------------------------------------------------------
extern "C" void kernel_launch(void* const* d_in, const int* in_sizes, int n_in,
                              void* d_out, int out_size, void* d_ws, size_t ws_size,
                              hipStream_t stream) {
  const float* xq = (const float*)d_in[0];
  const float* xk = (const float*)d_in[1];
  const float* xv = (const float*)d_in[2];
  const float* box = (const float*)d_in[3];
  const float* Wq = (const float*)d_in[4];
  const float* bq = (const float*)d_in[5];
  const float* Wk = (const float*)d_in[6];
  const float* bk = (const float*)d_in[7];
  const float* Wv = (const float*)d_in[8];
  const float* bv = (const float*)d_in[9];
  const float* Wo = (const float*)d_in[10];
  const float* bo = (const float*)d_in[11];
  const float* WGw = (const float*)d_in[12];
  const float* WGb = (const float*)d_in[13];

  size_t off = 0;
  char* wsc = (char*)d_ws;
  auto alloc = [&](size_t bytes) -> void* {
    void* p = wsc + off;
    off += (bytes + 255) & ~(size_t)255;
    return p;
  };
  bf16* xq_b = (bf16*)alloc((size_t)BN_ * D_ * 2);
  bf16* xk_b = (bf16*)alloc((size_t)BN_ * D_ * 2);
  bf16* xv_b = (bf16*)alloc((size_t)BN_ * D_ * 2);
  bf16* wq_b = (bf16*)alloc((size_t)D_ * D_ * 2);
  bf16* wk_b = (bf16*)alloc((size_t)D_ * D_ * 2);
  bf16* wv_b = (bf16*)alloc((size_t)D_ * D_ * 2);
  bf16* wo_b = (bf16*)alloc((size_t)D_ * D_ * 2);
  bf16* q_b = (bf16*)alloc((size_t)BN_ * D_ * 2);
  bf16* k_b = (bf16*)alloc((size_t)BN_ * D_ * 2);
  bf16* vt_b = (bf16*)alloc((size_t)BH_ * DK_ * NPAD_ * 2);
  bf16* ao_b = (bf16*)alloc((size_t)BN_ * D_ * 2);
  half_t* S = (half_t*)alloc((size_t)BH_ * N_ * NPAD_ * 2);

  const int n4x = BN_ * D_ / 4;
  const int n4w = D_ * D_ / 4;
  dim3 g3(n4x / 256, 3, 1);
  cvt3_kernel<<<g3, 256, 0, stream>>>(xq, xk, xv, xq_b, xk_b, xv_b, n4x);
  dim3 g4(n4w / 256, 4, 1);
  cvt4_kernel<<<g4, 256, 0, stream>>>(Wq, Wk, Wv, Wo, wq_b, wk_b, wv_b, wo_b, n4w);

  geo_kernel<<<(B_ * N_ * N_) / 256, 256, 0, stream>>>(box, WGw, WGb, S);

  // zero Vt so its pad columns (n in [196,224)) are 0, not poison
  hipMemsetAsync(vt_b, 0, (size_t)BH_ * DK_ * NPAD_ * 2, stream);

  dim3 gqkv(D_ / 128, BN_ / 128, 3);
  gemm3b<0><<<gqkv, 256, 0, stream>>>(xq_b, xk_b, xv_b, wq_b, wk_b, wv_b, bq, bk, bv,
                                      q_b, k_b, vt_b);

  attn_kernel<<<1024, 256, 0, stream>>>(q_b, k_b, vt_b, S, ao_b);

  dim3 gout(D_ / 128, BN_ / 128, 1);
  gemm3b<1><<<gout, 256, 0, stream>>>(ao_b, nullptr, nullptr, wo_b, nullptr, nullptr,
                                      bo, nullptr, nullptr, d_out, nullptr, nullptr);
}

// Round 7
// 315.006 us; speedup vs baseline: 1.1753x; 1.0160x over previous
//
#include <hip/hip_runtime.h>
#include <hip/hip_bf16.h>

typedef __bf16 bf16;
typedef _Float16 half_t;
typedef bf16 bf16x8 __attribute__((ext_vector_type(8)));
typedef bf16 bf16x4 __attribute__((ext_vector_type(4)));
typedef float floatx4 __attribute__((ext_vector_type(4)));

#define B_ 32
#define N_ 196
#define H_ 8
#define D_ 1024
#define DK_ 128
#define BN_ (B_ * N_)   // 6272
#define BH_ (B_ * H_)   // 256
#define NPAD_ 224       // padded N for S rows / Vt cols
#define PSTRIDE_ 232    // LDS P-tile col stride (16B aligned, bank-spread)

#define KT_ 16          // K tiles (BK=64), 1024 = 16*64 exact

typedef __attribute__((address_space(3))) unsigned int lds_uint;
typedef const __attribute__((address_space(1))) unsigned int glb_uint;

__device__ __forceinline__ void async_copy16(const bf16* g, bf16* l) {
  __builtin_amdgcn_global_load_lds((glb_uint*)g, (lds_uint*)l, 16, 0, 0);
}

#define BARRIER() asm volatile("s_barrier" ::: "memory")
#define WAITV0() asm volatile("s_waitcnt vmcnt(0)" ::: "memory")

// ---------------------------------------------------------------------------
// Batched f32 -> bf16 convert: blockIdx.y selects which tensor (same size).
// ---------------------------------------------------------------------------
__global__ __launch_bounds__(256) void cvt3_kernel(const float* __restrict__ s0,
                                                   const float* __restrict__ s1,
                                                   const float* __restrict__ s2,
                                                   bf16* __restrict__ d0,
                                                   bf16* __restrict__ d1,
                                                   bf16* __restrict__ d2, int n4) {
  const int which = blockIdx.y;
  const float* s = (which == 0) ? s0 : (which == 1) ? s1 : s2;
  bf16* d = (which == 0) ? d0 : (which == 1) ? d1 : d2;
  int i = blockIdx.x * 256 + threadIdx.x;
  if (i >= n4) return;
  float4 v = ((const float4*)s)[i];
  bf16x4 o;
  o[0] = (bf16)v.x;
  o[1] = (bf16)v.y;
  o[2] = (bf16)v.z;
  o[3] = (bf16)v.w;
  *(bf16x4*)(d + (size_t)i * 4) = o;
}

__global__ __launch_bounds__(256) void cvt4_kernel(const float* __restrict__ s0,
                                                   const float* __restrict__ s1,
                                                   const float* __restrict__ s2,
                                                   const float* __restrict__ s3,
                                                   bf16* __restrict__ d0,
                                                   bf16* __restrict__ d1,
                                                   bf16* __restrict__ d2,
                                                   bf16* __restrict__ d3, int n4) {
  const int which = blockIdx.y;
  const float* s = (which == 0) ? s0 : (which == 1) ? s1 : (which == 2) ? s2 : s3;
  bf16* d = (which == 0) ? d0 : (which == 1) ? d1 : (which == 2) ? d2 : d3;
  int i = blockIdx.x * 256 + threadIdx.x;
  if (i >= n4) return;
  float4 v = ((const float4*)s)[i];
  bf16x4 o;
  o[0] = (bf16)v.x;
  o[1] = (bf16)v.y;
  o[2] = (bf16)v.z;
  o[3] = (bf16)v.w;
  *(bf16x4*)(d + (size_t)i * 4) = o;
}

// ---------------------------------------------------------------------------
// Geometry weights (LINEAR domain): S[b,h,n,m] = max(relu(geo . WG_w[h] + b), 1e-6)
// stored f16. softmax(log w + s) == w*exp(s)/sum(w*exp(s)), so attn multiplies.
// ---------------------------------------------------------------------------
__global__ __launch_bounds__(256) void geo_kernel(const float* __restrict__ box,
                                                  const float* __restrict__ WGw,
                                                  const float* __restrict__ WGb,
                                                  half_t* __restrict__ S) {
  __shared__ float4 wsh[128];
  if (threadIdx.x < 128) wsh[threadIdx.x] = ((const float4*)WGw)[threadIdx.x];
  __syncthreads();

  int tid = blockIdx.x * 256 + threadIdx.x;
  int b = tid / (N_ * N_);
  int rem = tid - b * (N_ * N_);
  int n = rem / N_;
  int m = rem - n * N_;

  float4 bn = ((const float4*)box)[b * N_ + n];
  float4 bm = ((const float4*)box)[b * N_ + m];
  float cxn = (bn.x + bn.z) * 0.5f, cyn = (bn.y + bn.w) * 0.5f;
  float wn = bn.z - bn.x + 1.0f, hn = bn.w - bn.y + 1.0f;
  float cxm = (bm.x + bm.z) * 0.5f, cym = (bm.y + bm.w) * 0.5f;
  float wm = bm.z - bm.x + 1.0f, hm = bm.w - bm.y + 1.0f;

  float pos[4];
  pos[0] = __logf(fmaxf(fabsf((cxn - cxm) / wn), 1e-3f));
  pos[1] = __logf(fmaxf(fabsf((cyn - cym) / hn), 1e-3f));
  pos[2] = __logf(wn / wm);
  pos[3] = __logf(hn / hm);

  const float dims[8] = {1.0f,          0.4216965034f, 0.1778279410f, 0.0749894209f,
                         0.0316227766f, 0.0133352143f, 0.0056234133f, 0.0023713737f};
  float feat[64];
#pragma unroll
  for (int p = 0; p < 4; p++) {
#pragma unroll
    for (int f = 0; f < 8; f++) {
      float a = 100.0f * pos[p] * dims[f];
      feat[p * 8 + f] = __sinf(a);
      feat[32 + p * 8 + f] = __cosf(a);
    }
  }
#pragma unroll
  for (int hh = 0; hh < 8; hh++) {
    float accv = WGb[hh];
#pragma unroll
    for (int g4 = 0; g4 < 16; g4++) {
      float4 wv = wsh[hh * 16 + g4];
      accv += feat[g4 * 4 + 0] * wv.x + feat[g4 * 4 + 1] * wv.y +
              feat[g4 * 4 + 2] * wv.z + feat[g4 * 4 + 3] * wv.w;
    }
    S[((size_t)((b * H_ + hh) * N_ + n)) * NPAD_ + m] = (half_t)fmaxf(accv, 1e-6f);
  }
}

// ---------------------------------------------------------------------------
// 2-phase NT GEMM (round-5 measured-best structure) + XCD-chunked block
// swizzle (T1).  128x128 tile, BK=64, 4 waves (2M x 2N), per-wave 64x64,
// double-buffered LDS (64 KB -> 2 blocks/CU), 16-MFMA clusters, ONE
// barrier + ONE vmcnt(0) per K-tile, conflict-free XOR swizzle, setprio.
//
// XCD swizzle: HW dispatches flat f (x fastest), XCD = f%8 (m09 round-robin).
// Remap so XCD k owns logical chunk L in [k*chunk, (k+1)*chunk): within a
// chunk, x (N-tile / B-panel) cycles fastest, so the 8 blocks sharing one
// A-panel run on the SAME XCD concurrently -> panel fetched once per XCD.
// Bijective: f -> (k=f%8, s=f/8) -> L=k*chunk+s -> (lx=L%8, lyz=L/8).
//
// VARIANT 0: QKV (lz selects input/weight/bias; z<2 bf16 row-major,
//            z==2 writes Vt[(bh*DK+d)*NPAD+n]).  VARIANT 1: f32 row-major.
// ---------------------------------------------------------------------------
template <int VARIANT>
__global__ __launch_bounds__(256, 2) void gemm2p(
    const bf16* __restrict__ A0, const bf16* __restrict__ A1, const bf16* __restrict__ A2,
    const bf16* __restrict__ W0, const bf16* __restrict__ W1, const bf16* __restrict__ W2,
    const float* __restrict__ b0, const float* __restrict__ b1, const float* __restrict__ b2,
    void* __restrict__ O0, void* __restrict__ O1, void* __restrict__ O2) {
  __shared__ bf16 As[2][128 * 64];   // 2 x 16 KB
  __shared__ bf16 Bs[2][128 * 64];   // 2 x 16 KB

  // ---- XCD-chunked swizzle ----
  const int NZ = (VARIANT == 0) ? 3 : 1;
  const int chunk = 49 * NZ;                       // blocks per XCD (1176/8 or 392/8... = 147 / 49)
  const int f = blockIdx.x + (blockIdx.y << 3) + blockIdx.z * 392;
  const int L = (f & 7) * chunk + (f >> 3);
  const int lx = L & 7;                            // N-tile
  const int lyz = L >> 3;
  const int ly = (VARIANT == 0) ? (lyz % 49) : lyz;  // M-tile
  const int z = (VARIANT == 0) ? (lyz / 49) : 0;     // qkv select

  const bf16* A = (z == 0) ? A0 : (z == 1) ? A1 : A2;
  const bf16* W = (z == 0) ? W0 : (z == 1) ? W1 : W2;
  const float* bias = (z == 0) ? b0 : (z == 1) ? b1 : b2;

  const int tid = threadIdx.x;
  const int lane = tid & 63;
  const int wid = tid >> 6;
  const int l16 = lane & 15;
  const int quad = lane >> 4;
  const int wm = wid >> 1;   // 0..1 (M half)
  const int wn = wid & 1;    // 0..1 (N half)

  const bf16* gA = A + (size_t)ly * 128 * D_;
  const bf16* gB = W + (size_t)lx * 128 * D_;

  // staging: thread tid writes 16B at LDS slot (u*256 + tid); row = slot>>3,
  // phys 16B-slot = tid&7 holds logical slot (tid&7)^(row&7) under the XOR
  // swizzle -> pre-swizzled global source (rule #21).
  const int srow = tid >> 3;                        // 0..31
  const int lslot = (tid & 7) ^ (srow & 7);
  size_t sOff[4];
#pragma unroll
  for (int u = 0; u < 4; u++) sOff[u] = (size_t)(u * 32 + srow) * D_ + lslot * 8;

  // read offsets (elements): frag(row, kslot) at row*64 + ((kk*4+quad)^(row&7))*8
  int arow[4], brow[4], kslot[2];
#pragma unroll
  for (int i = 0; i < 4; i++) arow[i] = (wm * 64 + i * 16 + l16) * 64;
#pragma unroll
  for (int j = 0; j < 4; j++) brow[j] = (wn * 64 + j * 16 + l16) * 64;
#pragma unroll
  for (int kk = 0; kk < 2; kk++) kslot[kk] = ((kk * 4 + quad) ^ (l16 & 7)) * 8;

  floatx4 acc[4][4];
#pragma unroll
  for (int i = 0; i < 4; i++)
#pragma unroll
    for (int j = 0; j < 4; j++)
#pragma unroll
      for (int r = 0; r < 4; r++) acc[i][j][r] = 0.0f;

  // ---- prologue: stage tile 0 into buffer 0 ----
#pragma unroll
  for (int u = 0; u < 4; u++) {
    async_copy16(gA + sOff[u], &As[0][u * 2048 + tid * 8]);
    async_copy16(gB + sOff[u], &Bs[0][u * 2048 + tid * 8]);
  }
  WAITV0();
  BARRIER();

  // ---- main loop ----
  for (int kt = 0; kt < KT_; ++kt) {
    const int cur = kt & 1;
    const bf16* Ab = As[cur];
    const bf16* Bb = Bs[cur];
    const bool pf = (kt + 1 < KT_);
    const bf16* pa = gA + (kt + 1) * 64;
    const bf16* pb = gB + (kt + 1) * 64;
    bf16* dA = As[cur ^ 1];
    bf16* dB = Bs[cur ^ 1];
    bf16x8 af[4], bfv[4];

    // ---- phase 0 (kk=0): 8 ds_read + 4 A-stage + 16 MFMA ----
#pragma unroll
    for (int i = 0; i < 4; i++) af[i] = *(const bf16x8*)(Ab + arow[i] + kslot[0]);
#pragma unroll
    for (int j = 0; j < 4; j++) bfv[j] = *(const bf16x8*)(Bb + brow[j] + kslot[0]);
    if (pf) {
#pragma unroll
      for (int u = 0; u < 4; u++) async_copy16(pa + sOff[u], dA + u * 2048 + tid * 8);
    }
    __builtin_amdgcn_s_setprio(1);
#pragma unroll
    for (int i = 0; i < 4; i++)
#pragma unroll
      for (int j = 0; j < 4; j++)
        acc[i][j] = __builtin_amdgcn_mfma_f32_16x16x32_bf16(af[i], bfv[j], acc[i][j], 0, 0, 0);
    __builtin_amdgcn_s_setprio(0);

    // ---- phase 1 (kk=1): 8 ds_read + 4 B-stage + 16 MFMA ----
#pragma unroll
    for (int i = 0; i < 4; i++) af[i] = *(const bf16x8*)(Ab + arow[i] + kslot[1]);
#pragma unroll
    for (int j = 0; j < 4; j++) bfv[j] = *(const bf16x8*)(Bb + brow[j] + kslot[1]);
    if (pf) {
#pragma unroll
      for (int u = 0; u < 4; u++) async_copy16(pb + sOff[u], dB + u * 2048 + tid * 8);
    }
    __builtin_amdgcn_s_setprio(1);
#pragma unroll
    for (int i = 0; i < 4; i++)
#pragma unroll
      for (int j = 0; j < 4; j++)
        acc[i][j] = __builtin_amdgcn_mfma_f32_16x16x32_bf16(af[i], bfv[j], acc[i][j], 0, 0, 0);
    __builtin_amdgcn_s_setprio(0);

    // ---- tile boundary: drain next buffer's stage loads, sync ----
    if (pf) {
      WAITV0();
      BARRIER();
    }
  }

  // ---- epilogue ----
  const int m0 = ly * 128 + wm * 64;
  const int n0 = lx * 128 + wn * 64;
#pragma unroll
  for (int j = 0; j < 4; j++) {
    const int col = n0 + j * 16 + l16;
    const float bv = bias[col];
#pragma unroll
    for (int i = 0; i < 4; i++) {
#pragma unroll
      for (int r = 0; r < 4; r++) {
        const int row = m0 + i * 16 + quad * 4 + r;
        float v = acc[i][j][r] + bv;
        if (VARIANT == 1) {
          ((float*)O0)[(size_t)row * D_ + col] = v;
        } else if (z < 2) {
          bf16* Cout = z ? (bf16*)O1 : (bf16*)O0;
          Cout[(size_t)row * D_ + col] = (bf16)v;
        } else {
          int b = row / N_;
          int n = row - b * N_;
          int h = col >> 7;
          int d = col & (DK_ - 1);
          ((bf16*)O2)[((size_t)((b * H_ + h) * DK_ + d)) * NPAD_ + n] = (bf16)v;
        }
      }
    }
  }
}

// ---------------------------------------------------------------------------
// Fused attention (round-6 version, unchanged): per block = one (b,h) x 64
// Q-rows.  K and V staged into LDS (coalesced global_load_lds, dbuf,
// XOR swizzle).  K-LDS unioned with P-tile.  QK^T + LINEAR geo weight +
// softmax + P->LDS + PV -> AO.
// ---------------------------------------------------------------------------
__global__ __launch_bounds__(256) void attn_kernel(const bf16* __restrict__ Q,
                                                   const bf16* __restrict__ Kmat,
                                                   const bf16* __restrict__ Vt,
                                                   const half_t* __restrict__ Sb,
                                                   bf16* __restrict__ AO) {
  // smem layout: [0, 29696) = Pl (4*16*PSTRIDE_ bf16) UNION Ks[2][32*128];
  //              [29696, 46080) = Vs[2][128*32]
  __shared__ alignas(16) char smem[46080];
  bf16* KsB[2] = {(bf16*)smem, (bf16*)smem + 4096};
  bf16* Pl = (bf16*)smem;
  bf16* VsB[2] = {(bf16*)(smem + 29696), (bf16*)(smem + 29696) + 4096};

  const int f = blockIdx.x;
  const int tile = (f >> 3) & 3;
  const int bh = (f & 7) | ((f >> 5) << 3);      // tiles of one bh are 8 apart -> same XCD
  const int b = bh >> 3;
  const int h = bh & 7;
  const int tid = threadIdx.x;
  const int wave = tid >> 6;
  const int lane = tid & 63;
  const int l16 = lane & 15;
  const int quad = lane >> 4;
  const int nrb = tile * 64 + wave * 16;

  size_t kSrc[2];
  int kDst[2];
#pragma unroll
  for (int u = 0; u < 2; u++) {
    const int slot = u * 256 + tid;
    const int srow = slot >> 4;
    const int scs = slot & 15;
    kSrc[u] = (size_t)(b * N_ + srow) * D_ + h * DK_ + (scs ^ (srow & 7)) * 8;
    kDst[u] = slot * 8;
  }
  size_t vSrc[2];
#pragma unroll
  for (int u = 0; u < 2; u++) {
    const int slot = u * 256 + tid;
    const int vrow = slot >> 2;
    const int vcs = slot & 3;
    vSrc[u] = (size_t)bh * DK_ * NPAD_ + (size_t)vrow * NPAD_ + (vcs ^ (vrow & 3)) * 8;
  }

  // ---- prologue: stage K tile 0; load Q fragments ----
#pragma unroll
  for (int u = 0; u < 2; u++) async_copy16(Kmat + kSrc[u], KsB[0] + kDst[u]);

  const int na = nrb + l16;
  const bool nav = na < N_;
  const bf16* aptr = Q + ((size_t)(b * N_ + (nav ? na : 0))) * D_ + h * DK_ + quad * 8;
  bf16x8 afr[4];
#pragma unroll
  for (int kk = 0; kk < 4; kk++) {
    bf16x8 v = *(const bf16x8*)(aptr + kk * 32);
    if (!nav) {
#pragma unroll
      for (int e = 0; e < 8; e++) v[e] = (bf16)0.0f;
    }
    afr[kk] = v;
  }
  WAITV0();
  BARRIER();

  // ---- QK^T over 7 K-tiles of 32 rows (dbuf) ----
  floatx4 S[14];
#pragma unroll
  for (int j = 0; j < 14; j++)
#pragma unroll
    for (int r = 0; r < 4; r++) S[j][r] = 0.0f;

  for (int jt = 0; jt < 7; ++jt) {
    const int cur = jt & 1;
    if (jt < 6) {
      const size_t koff = (size_t)((jt + 1) * 32) * D_;
#pragma unroll
      for (int u = 0; u < 2; u++)
        async_copy16(Kmat + kSrc[u] + koff, KsB[cur ^ 1] + kDst[u]);
    }
    const bf16* Kb = KsB[cur];
    __builtin_amdgcn_s_setprio(1);
#pragma unroll
    for (int jj = 0; jj < 2; jj++) {
      const int mloc = jj * 16 + l16;
#pragma unroll
      for (int kk = 0; kk < 4; kk++) {
        bf16x8 bb = *(const bf16x8*)(Kb + mloc * 128 + ((kk * 4 + quad) ^ (l16 & 7)) * 8);
        S[jt * 2 + jj] = __builtin_amdgcn_mfma_f32_16x16x32_bf16(afr[kk], bb, S[jt * 2 + jj], 0, 0, 0);
      }
    }
    __builtin_amdgcn_s_setprio(0);
    if (jt < 6) {
      WAITV0();
      BARRIER();
    }
  }

  // early V-tile-0 stage (overlaps softmax; lands by the __syncthreads drain)
#pragma unroll
  for (int u = 0; u < 2; u++) async_copy16(Vt + vSrc[u], VsB[0] + kDst[u]);

  // all waves done reading Ks before Pl (same LDS region) is written
  BARRIER();

  // ---- scale + mask + max + weighted exp + P->LDS ----
  const float scale = 0.08838834764831845f;  // 1/sqrt(128)
  const half_t* bbase = Sb + ((size_t)bh * N_) * NPAD_;
  bf16* pw = Pl + wave * 16 * PSTRIDE_;
  float inv[4];
#pragma unroll
  for (int r = 0; r < 4; r++) {
    const int n = nrb + quad * 4 + r;
    const bool nv = n < N_;
    const size_t brow = (size_t)(nv ? n : 0) * NPAD_;
    float mx = -1e30f;
#pragma unroll
    for (int j = 0; j < 14; j++) {
      const int m = j * 16 + l16;
      float s = (nv && m < N_) ? S[j][r] * scale : -1e30f;
      S[j][r] = s;
      mx = fmaxf(mx, s);
    }
#pragma unroll
    for (int off = 1; off < 16; off <<= 1) mx = fmaxf(mx, __shfl_xor(mx, off, 64));
    float sum = 0.0f;
#pragma unroll
    for (int j = 0; j < 14; j++) {
      const int m = j * 16 + l16;
      float w = (m < N_) ? (float)bbase[brow + m] : 0.0f;
      float e = w * __expf(S[j][r] - mx);
      sum += e;
      pw[(quad * 4 + r) * PSTRIDE_ + m] = (bf16)e;
    }
#pragma unroll
    for (int off = 1; off < 16; off <<= 1) sum += __shfl_xor(sum, off, 64);
    inv[r] = 1.0f / sum;
  }
  __syncthreads();   // drains vmcnt too: V tile 0 landed, P visible

  // ---- PV over 7 n-tiles of 32 cols (dbuf) ----
  floatx4 O[8];
#pragma unroll
  for (int j2 = 0; j2 < 8; j2++)
#pragma unroll
    for (int r = 0; r < 4; r++) O[j2][r] = 0.0f;

  const bf16* pr = pw + l16 * PSTRIDE_ + quad * 8;
  for (int t7 = 0; t7 < 7; ++t7) {
    const int cur = t7 & 1;
    if (t7 < 6) {
      const size_t voff = (size_t)((t7 + 1) * 32);
#pragma unroll
      for (int u = 0; u < 2; u++)
        async_copy16(Vt + vSrc[u] + voff, VsB[cur ^ 1] + kDst[u]);
    }
    const bf16* Vb = VsB[cur];
    bf16x8 a = *(const bf16x8*)(pr + t7 * 32);
    __builtin_amdgcn_s_setprio(1);
#pragma unroll
    for (int j2 = 0; j2 < 8; j2++) {
      bf16x8 bb = *(const bf16x8*)(Vb + (j2 * 16 + l16) * 32 + (quad ^ (l16 & 3)) * 8);
      O[j2] = __builtin_amdgcn_mfma_f32_16x16x32_bf16(a, bb, O[j2], 0, 0, 0);
    }
    __builtin_amdgcn_s_setprio(0);
    if (t7 < 6) {
      WAITV0();
      BARRIER();
    }
  }

  // ---- epilogue: scale by 1/l, store ----
#pragma unroll
  for (int r = 0; r < 4; r++) {
    const int n = nrb + quad * 4 + r;
    if (n < N_) {
#pragma unroll
      for (int j2 = 0; j2 < 8; j2++) {
        AO[((size_t)(b * N_ + n)) * D_ + h * DK_ + j2 * 16 + l16] = (bf16)(O[j2][r] * inv[r]);
      }
    }
  }
}

// ---------------------------------------------------------------------------
extern "C" void kernel_launch(void* const* d_in, const int* in_sizes, int n_in,
                              void* d_out, int out_size, void* d_ws, size_t ws_size,
                              hipStream_t stream) {
  const float* xq = (const float*)d_in[0];
  const float* xk = (const float*)d_in[1];
  const float* xv = (const float*)d_in[2];
  const float* box = (const float*)d_in[3];
  const float* Wq = (const float*)d_in[4];
  const float* bq = (const float*)d_in[5];
  const float* Wk = (const float*)d_in[6];
  const float* bk = (const float*)d_in[7];
  const float* Wv = (const float*)d_in[8];
  const float* bv = (const float*)d_in[9];
  const float* Wo = (const float*)d_in[10];
  const float* bo = (const float*)d_in[11];
  const float* WGw = (const float*)d_in[12];
  const float* WGb = (const float*)d_in[13];

  size_t off = 0;
  char* wsc = (char*)d_ws;
  auto alloc = [&](size_t bytes) -> void* {
    void* p = wsc + off;
    off += (bytes + 255) & ~(size_t)255;
    return p;
  };
  bf16* xq_b = (bf16*)alloc((size_t)BN_ * D_ * 2);
  bf16* xk_b = (bf16*)alloc((size_t)BN_ * D_ * 2);
  bf16* xv_b = (bf16*)alloc((size_t)BN_ * D_ * 2);
  bf16* wq_b = (bf16*)alloc((size_t)D_ * D_ * 2);
  bf16* wk_b = (bf16*)alloc((size_t)D_ * D_ * 2);
  bf16* wv_b = (bf16*)alloc((size_t)D_ * D_ * 2);
  bf16* wo_b = (bf16*)alloc((size_t)D_ * D_ * 2);
  bf16* q_b = (bf16*)alloc((size_t)BN_ * D_ * 2);
  bf16* k_b = (bf16*)alloc((size_t)BN_ * D_ * 2);
  bf16* vt_b = (bf16*)alloc((size_t)BH_ * DK_ * NPAD_ * 2);
  bf16* ao_b = (bf16*)alloc((size_t)BN_ * D_ * 2);
  half_t* S = (half_t*)alloc((size_t)BH_ * N_ * NPAD_ * 2);

  const int n4x = BN_ * D_ / 4;
  const int n4w = D_ * D_ / 4;
  dim3 g3(n4x / 256, 3, 1);
  cvt3_kernel<<<g3, 256, 0, stream>>>(xq, xk, xv, xq_b, xk_b, xv_b, n4x);
  dim3 g4(n4w / 256, 4, 1);
  cvt4_kernel<<<g4, 256, 0, stream>>>(Wq, Wk, Wv, Wo, wq_b, wk_b, wv_b, wo_b, n4w);

  geo_kernel<<<(B_ * N_ * N_) / 256, 256, 0, stream>>>(box, WGw, WGb, S);

  // zero Vt so its pad columns (n in [196,224)) are 0, not poison
  hipMemsetAsync(vt_b, 0, (size_t)BH_ * DK_ * NPAD_ * 2, stream);

  dim3 gqkv(D_ / 128, BN_ / 128, 3);
  gemm2p<0><<<gqkv, 256, 0, stream>>>(xq_b, xk_b, xv_b, wq_b, wk_b, wv_b, bq, bk, bv,
                                      q_b, k_b, vt_b);

  attn_kernel<<<1024, 256, 0, stream>>>(q_b, k_b, vt_b, S, ao_b);

  dim3 gout(D_ / 128, BN_ / 128, 1);
  gemm2p<1><<<gout, 256, 0, stream>>>(ao_b, nullptr, nullptr, wo_b, nullptr, nullptr,
                                      bo, nullptr, nullptr, d_out, nullptr, nullptr);
}